// Round 5
// baseline (181.998 us; speedup 1.0000x reference)
//
#include <hip/hip_runtime.h>
#include <hip/hip_bf16.h>

#define NN   4096
#define FIN  512
#define NH   4
#define DD   64

typedef float f32x4 __attribute__((ext_vector_type(4)));
typedef short s16x8 __attribute__((ext_vector_type(8)));

// manual RNE float->bf16
__device__ __forceinline__ short bfbits(float f) {
  union { float f; unsigned u; } v; v.f = f;
  unsigned r = v.u + 0x7FFFu + ((v.u >> 16) & 1u);
  return (short)(r >> 16);
}

// packed pair float->bf16
__device__ __forceinline__ int pkbf(float a, float b) {
  union { float f; unsigned u; } va, vb;
  va.f = a; vb.f = b;
  unsigned ra = (va.u + 0x7FFFu + ((va.u >> 16) & 1u)) >> 16;
  unsigned rb = (vb.u + 0x7FFFu + ((vb.u >> 16) & 1u)) & 0xFFFF0000u;
  return (int)(ra | rb);
}

__device__ __forceinline__ float hexp2(float x) {
#if __has_builtin(__builtin_amdgcn_exp2f)
  return __builtin_amdgcn_exp2f(x);
#else
  return __builtin_exp2f(x);
#endif
}

// ---------------------------------------------------------------------------
// Kernel 1: Wx = X @ W[h] (bf16 MFMA). grid 512 = rowtile32(128) x head(4),
// 256 thr = 4 waves (2 row-halves x 2 col-halves). 2 blocks/CU so barrier
// stalls overlap across blocks. Outputs WxT[h][d][n] bf16 + scaled s_src/s_dst.
// ---------------------------------------------------------------------------
__global__ __launch_bounds__(256) void gat_k1(
    const float* __restrict__ x, const float* __restrict__ W,
    const float* __restrict__ a,
    short* __restrict__ WxT, float* __restrict__ ssrc, float* __restrict__ sdst)
{
  __shared__ short As[32 * 72];   // [row][k] bf16, K-chunk 64, pad 72
  __shared__ short Bs[64 * 72];   // [d][k] bf16
  __shared__ float Cs[64 * 33];   // [d][n] fp32 for epilogue

  const int blk = blockIdx.x;
  const int h  = blk & 3;
  const int rr = blk >> 2;        // 0..127
  const int n0 = rr * 32;
  const int t  = threadIdx.x;
  const int w  = t >> 6, lane = t & 63;
  const int lm = lane & 15, q = lane >> 4;
  const int wr = w & 1, wc = w >> 1;

  f32x4 acc[2] = {};
  const float* Wh = W + (size_t)h * (FIN * DD);

  for (int kq = 0; kq < 8; ++kq) {
    // stage A: x[n0+row][kq*64 + fc .. +8)
    {
      const int row = t >> 3, fc = (t & 7) * 8;
      const float* xp = x + (size_t)(n0 + row) * FIN + kq * 64 + fc;
      float4 v0 = ((const float4*)xp)[0];
      float4 v1 = ((const float4*)xp)[1];
      union { short s[8]; int4 v; } u;
      u.s[0]=bfbits(v0.x); u.s[1]=bfbits(v0.y); u.s[2]=bfbits(v0.z); u.s[3]=bfbits(v0.w);
      u.s[4]=bfbits(v1.x); u.s[5]=bfbits(v1.y); u.s[6]=bfbits(v1.z); u.s[7]=bfbits(v1.w);
      *(int4*)(As + row * 72 + fc) = u.v;
    }
    // stage B transposed: W[h][kq*64+fl][dc..dc+16) -> Bs[d][fl]
    {
      const int fl = t >> 2, dc = (t & 3) * 16;
      const float* wp = Wh + (size_t)(kq * 64 + fl) * DD + dc;
      float4 w0 = ((const float4*)wp)[0];
      float4 w1 = ((const float4*)wp)[1];
      float4 w2 = ((const float4*)wp)[2];
      float4 w3 = ((const float4*)wp)[3];
      Bs[(dc+ 0)*72+fl]=bfbits(w0.x); Bs[(dc+ 1)*72+fl]=bfbits(w0.y);
      Bs[(dc+ 2)*72+fl]=bfbits(w0.z); Bs[(dc+ 3)*72+fl]=bfbits(w0.w);
      Bs[(dc+ 4)*72+fl]=bfbits(w1.x); Bs[(dc+ 5)*72+fl]=bfbits(w1.y);
      Bs[(dc+ 6)*72+fl]=bfbits(w1.z); Bs[(dc+ 7)*72+fl]=bfbits(w1.w);
      Bs[(dc+ 8)*72+fl]=bfbits(w2.x); Bs[(dc+ 9)*72+fl]=bfbits(w2.y);
      Bs[(dc+10)*72+fl]=bfbits(w2.z); Bs[(dc+11)*72+fl]=bfbits(w2.w);
      Bs[(dc+12)*72+fl]=bfbits(w3.x); Bs[(dc+13)*72+fl]=bfbits(w3.y);
      Bs[(dc+14)*72+fl]=bfbits(w3.z); Bs[(dc+15)*72+fl]=bfbits(w3.w);
    }
    __syncthreads();
#pragma unroll
    for (int s = 0; s < 2; ++s) {
      s16x8 af = *(const s16x8*)(As + (wr * 16 + lm) * 72 + s * 32 + q * 8);
#pragma unroll
      for (int c = 0; c < 2; ++c) {
        s16x8 bf = *(const s16x8*)(Bs + (wc * 32 + c * 16 + lm) * 72 + s * 32 + q * 8);
        acc[c] = __builtin_amdgcn_mfma_f32_16x16x32_bf16(af, bf, acc[c], 0, 0, 0);
      }
    }
    __syncthreads();
  }

  // scatter C transposed into Cs[d][n]  (C layout: col=lm, row=q*4+g)
#pragma unroll
  for (int c = 0; c < 2; ++c)
#pragma unroll
    for (int g = 0; g < 4; ++g)
      Cs[(wc * 32 + c * 16 + lm) * 33 + (wr * 16 + q * 4 + g)] = acc[c][g];
  __syncthreads();

  // epilogue 1: WxT[h][d][n0..n0+32) bf16
  {
    const int d = t >> 2, nc = (t & 3) * 8;
    union { short s[8]; int4 v; } u;
#pragma unroll
    for (int e = 0; e < 8; ++e) u.s[e] = bfbits(Cs[d * 33 + nc + e]);
    *(int4*)(WxT + (size_t)(h * 64 + d) * NN + n0 + nc) = u.v;
  }
  // epilogue 2: s_src / s_dst (scaled by log2 e)
  if (t < 64) {
    const int n = t & 31;
    const int isdst = t >> 5;
    const float* av = a + h * 128 + isdst * 64;
    float s = 0.f;
#pragma unroll 8
    for (int d = 0; d < 64; ++d) s = fmaf(Cs[d * 33 + n], av[d], s);
    const float LOG2E = 1.4426950408889634f;
    (isdst ? sdst : ssrc)[h * NN + n0 + n] = s * LOG2E;
  }
}

// ---------------------------------------------------------------------------
// Kernel 2: barrier-free flash-GAT. 2048 independent waves:
// (128 rowtiles of 32) x (4 heads) x (4 j-chunks of 1024).
// V fragments loaded DIRECTLY from global WxT (L2-resident, 16B/lane
// contiguous) -- no LDS staging, no __syncthreads in the j-loop.
// Block = 1 rowtile x 2 heads x 4 j-chunks (8 waves); blockIdx swizzled so
// the two head-pair blocks of a rowtile share an XCD (round-robin %8).
// End: LDS merge of the 4 j-chunks + epilogue (1 barrier).
// ---------------------------------------------------------------------------
__global__ __launch_bounds__(512, 2) void gat_k2(
    const int* __restrict__ adj, const short* __restrict__ WxT,
    const float* __restrict__ ssrc, const float* __restrict__ sdst,
    const float* __restrict__ bias, float* __restrict__ out)
{
  __shared__ float MRG[6][32][68];   // [hp*3 + jc-1][row][col]
  __shared__ float Lm[2][4][32];     // [hp][jc][row] row-sums

  const int blk = blockIdx.x;
  // blk = (rrHi)*16 + hpair*8 + rrLo  -> same-rowtile blocks 8 apart (same XCD)
  const int rr    = ((blk >> 4) << 3) | (blk & 7);   // 0..127
  const int hpair = (blk >> 3) & 1;
  const int t = threadIdx.x;
  const int w = t >> 6, lane = t & 63;
  const int lm = lane & 15, q = lane >> 4;
  const int hp = w & 1;            // head within pair
  const int h  = hpair * 2 + hp;
  const int jc = w >> 1;           // j-chunk 0..3
  const int jbase = jc * 1024;
  const int ib = rr * 32;
  const int i0 = ib + lm, i1 = i0 + 16;

  const float src0 = ssrc[h * NN + i0] - 1000.0f;
  const float src1 = ssrc[h * NN + i1] - 1000.0f;

  const short one = 0x3F80;
  s16x8 bones = {};
  if (lm == 0) {
    bones[0]=one; bones[1]=one; bones[2]=one; bones[3]=one;
    bones[4]=one; bones[5]=one; bones[6]=one; bones[7]=one;
  }

  f32x4 acc[2][4] = {};
  f32x4 accl[2] = {};

  const short* Vb    = WxT + (size_t)(h * 64) * NN;
  const int*   arow0 = adj + (size_t)i0 * NN;
  const int*   arow1 = adj + (size_t)i1 * NN;
  const float* sdh   = sdst + h * NN;

#pragma unroll 2
  for (int js = 0; js < 32; ++js) {
    const int j0 = jbase + js * 32 + q * 8;

    s16x8 bf[4];
#pragma unroll
    for (int c = 0; c < 4; ++c)
      bf[c] = *(const s16x8*)(Vb + (size_t)(c * 16 + lm) * NN + j0);

    const int4* A0p = (const int4*)(arow0 + j0);
    const int4* A1p = (const int4*)(arow1 + j0);
    int4 A00 = A0p[0], A01 = A0p[1];
    int4 A10 = A1p[0], A11 = A1p[1];
    const float4* Sp = (const float4*)(sdh + j0);
    float4 S0 = Sp[0], S1 = Sp[1];

#pragma unroll
    for (int rf = 0; rf < 2; ++rf) {
      const float src_i = rf ? src1 : src0;
      const int4 Aa = rf ? A10 : A00;
      const int4 Ab = rf ? A11 : A01;
      float p[8];
#define PGEN(dv, av, idx)                                                     \
      { float tp = src_i + (dv);                                              \
        float u  = fmaxf(tp, fmaf(tp, 0.2f, -800.0f));                        \
        u = fmaf((float)(av), 1000.0f, u);                                    \
        p[idx] = hexp2(u); }
      PGEN(S0.x, Aa.x, 0) PGEN(S0.y, Aa.y, 1)
      PGEN(S0.z, Aa.z, 2) PGEN(S0.w, Aa.w, 3)
      PGEN(S1.x, Ab.x, 4) PGEN(S1.y, Ab.y, 5)
      PGEN(S1.z, Ab.z, 6) PGEN(S1.w, Ab.w, 7)
#undef PGEN
      union { int i4[4]; s16x8 v; } af;
      af.i4[0] = pkbf(p[0], p[1]);
      af.i4[1] = pkbf(p[2], p[3]);
      af.i4[2] = pkbf(p[4], p[5]);
      af.i4[3] = pkbf(p[6], p[7]);
#pragma unroll
      for (int c = 0; c < 4; ++c)
        acc[rf][c] = __builtin_amdgcn_mfma_f32_16x16x32_bf16(af.v, bf[c], acc[rf][c], 0, 0, 0);
      accl[rf] = __builtin_amdgcn_mfma_f32_16x16x32_bf16(af.v, bones, accl[rf], 0, 0, 0);
    }
  }

  // ---- merge the 4 j-chunks per (head, rowtile) ----
  if (jc != 0) {
#pragma unroll
    for (int rf = 0; rf < 2; ++rf)
#pragma unroll
      for (int c = 0; c < 4; ++c)
#pragma unroll
        for (int g = 0; g < 4; ++g)
          MRG[hp * 3 + jc - 1][rf * 16 + q * 4 + g][c * 16 + lm] = acc[rf][c][g];
  }
  if (lm == 0) {
#pragma unroll
    for (int rf = 0; rf < 2; ++rf)
#pragma unroll
      for (int g = 0; g < 4; ++g)
        Lm[hp][jc][rf * 16 + q * 4 + g] = accl[rf][g];
  }
  __syncthreads();
  if (jc == 0) {
#pragma unroll
    for (int rf = 0; rf < 2; ++rf) {
#pragma unroll
      for (int g = 0; g < 4; ++g) {
        const int row = rf * 16 + q * 4 + g;
        const float l = Lm[hp][0][row] + Lm[hp][1][row] + Lm[hp][2][row] + Lm[hp][3][row];
        const float inv = 1.0f / l;
        const int grow = ib + row;
#pragma unroll
        for (int c = 0; c < 4; ++c) {
          const int col = c * 16 + lm;
          float v = acc[rf][c][g]
                  + MRG[hp * 3 + 0][row][col]
                  + MRG[hp * 3 + 1][row][col]
                  + MRG[hp * 3 + 2][row][col];
          float o = fmaf(v, inv, bias[h * 64 + col]);
          out[(size_t)grow * 256 + h * 64 + col] = fmaxf(o, 0.0f);
        }
      }
    }
  }
}

// ---------------------------------------------------------------------------
extern "C" void kernel_launch(void* const* d_in, const int* in_sizes, int n_in,
                              void* d_out, int out_size, void* d_ws, size_t ws_size,
                              hipStream_t stream) {
  const float* x    = (const float*)d_in[0];
  const int*   adj  = (const int*)d_in[1];
  const float* W    = (const float*)d_in[2];
  const float* a    = (const float*)d_in[3];
  const float* bias = (const float*)d_in[4];
  float* out = (float*)d_out;

  short* WxT  = (short*)d_ws;                                  // 2 MB bf16
  float* ssrc = (float*)((char*)d_ws + (size_t)NH * DD * NN * 2);
  float* sdst = ssrc + NH * NN;

  gat_k1<<<512, 256, 0, stream>>>(x, W, a, WxT, ssrc, sdst);
  gat_k2<<<256, 512, 0, stream>>>(adj, WxT, ssrc, sdst, bias, out);
}

// Round 6
// 177.206 us; speedup vs baseline: 1.0270x; 1.0270x over previous
//
#include <hip/hip_runtime.h>
#include <hip/hip_bf16.h>

#define NN   4096
#define FIN  512
#define NH   4
#define DD   64

typedef float f32x4 __attribute__((ext_vector_type(4)));
typedef short s16x8 __attribute__((ext_vector_type(8)));

// manual RNE float->bf16
__device__ __forceinline__ short bfbits(float f) {
  union { float f; unsigned u; } v; v.f = f;
  unsigned r = v.u + 0x7FFFu + ((v.u >> 16) & 1u);
  return (short)(r >> 16);
}

// packed pair float->bf16
__device__ __forceinline__ int pkbf(float a, float b) {
  union { float f; unsigned u; } va, vb;
  va.f = a; vb.f = b;
  unsigned ra = (va.u + 0x7FFFu + ((va.u >> 16) & 1u)) >> 16;
  unsigned rb = (vb.u + 0x7FFFu + ((vb.u >> 16) & 1u)) & 0xFFFF0000u;
  return (int)(ra | rb);
}

__device__ __forceinline__ float hexp2(float x) {
#if __has_builtin(__builtin_amdgcn_exp2f)
  return __builtin_amdgcn_exp2f(x);
#else
  return __builtin_exp2f(x);
#endif
}

// ---------------------------------------------------------------------------
// Kernel 1: Wx = X @ W[h], split-K, NO in-loop barriers.
// grid 1024 = rowtile32(128) x head(4) x dhalf(2); 256 thr = 4 waves, each
// wave owns a K-quarter (128 k). A/B frags loaded directly from global
// (W tile is L1-hot). End: LDS merge + transposed coalesced bf16 store +
// atomicAdd of pre-scaled s_src/s_dst partials.
// ---------------------------------------------------------------------------
__global__ __launch_bounds__(256, 4) void gat_k1(
    const float* __restrict__ x, const float* __restrict__ W,
    const float* __restrict__ a,
    short* __restrict__ WxT, float* __restrict__ ssrc, float* __restrict__ sdst)
{
  __shared__ float Ms[3][32][34];   // K-split merge
  __shared__ float Td[32][33];      // [d][n] transposed tile for epilogue

  const int b  = blockIdx.x;
  const int rt = b >> 3;            // 0..127
  const int h  = (b >> 1) & 3;
  const int dh = b & 1;
  const int n0 = rt * 32;
  const int t  = threadIdx.x;
  const int w  = t >> 6, lane = t & 63;
  const int lm = lane & 15, q = lane >> 4;

  const float* Wh = W + (size_t)h * (FIN * DD) + dh * 32;
  f32x4 acc[2][2] = {};

#pragma unroll
  for (int ks = 0; ks < 4; ++ks) {
    const int k0 = w * 128 + ks * 32 + q * 8;
    // A fragments: x[n0 + rf*16 + lm][k0 .. k0+7]
    s16x8 af[2];
#pragma unroll
    for (int rf = 0; rf < 2; ++rf) {
      const float* xp = x + (size_t)(n0 + rf * 16 + lm) * FIN + k0;
      float4 a0 = ((const float4*)xp)[0];
      float4 a1 = ((const float4*)xp)[1];
      union { short s[8]; s16x8 v; } u;
      u.s[0]=bfbits(a0.x); u.s[1]=bfbits(a0.y); u.s[2]=bfbits(a0.z); u.s[3]=bfbits(a0.w);
      u.s[4]=bfbits(a1.x); u.s[5]=bfbits(a1.y); u.s[6]=bfbits(a1.z); u.s[7]=bfbits(a1.w);
      af[rf] = u.v;
    }
    // B fragments: W[h][k0+e][dh*32 + c*16 + lm]
    s16x8 bfr[2];
#pragma unroll
    for (int c = 0; c < 2; ++c) {
      const float* wp = Wh + (size_t)k0 * DD + c * 16 + lm;
      union { short s[8]; s16x8 v; } u;
#pragma unroll
      for (int e = 0; e < 8; ++e) u.s[e] = bfbits(wp[e * DD]);
      bfr[c] = u.v;
    }
#pragma unroll
    for (int rf = 0; rf < 2; ++rf)
#pragma unroll
      for (int c = 0; c < 2; ++c)
        acc[rf][c] = __builtin_amdgcn_mfma_f32_16x16x32_bf16(af[rf], bfr[c], acc[rf][c], 0, 0, 0);
  }

  // merge K-quarters (C layout: col = c*16+lm, row = rf*16 + q*4 + g)
  if (w != 0) {
#pragma unroll
    for (int rf = 0; rf < 2; ++rf)
#pragma unroll
      for (int c = 0; c < 2; ++c)
#pragma unroll
        for (int g = 0; g < 4; ++g)
          Ms[w - 1][rf * 16 + q * 4 + g][c * 16 + lm] = acc[rf][c][g];
  }
  __syncthreads();
  if (w == 0) {
#pragma unroll
    for (int rf = 0; rf < 2; ++rf)
#pragma unroll
      for (int c = 0; c < 2; ++c)
#pragma unroll
        for (int g = 0; g < 4; ++g) {
          const int row = rf * 16 + q * 4 + g, col = c * 16 + lm;
          float v = acc[rf][c][g] + Ms[0][row][col] + Ms[1][row][col] + Ms[2][row][col];
          Td[col][row] = v;   // transposed: [d][n]
        }
  }
  __syncthreads();

  // epilogue 1: WxT[h*64 + dh*32 + d][n0 + nc .. +3] bf16, coalesced-ish
  {
    const int d = t >> 3, nc = (t & 7) * 4;
    union { short s[4]; int2 v; } u;
#pragma unroll
    for (int e = 0; e < 4; ++e) u.s[e] = bfbits(Td[d][nc + e]);
    *(int2*)(WxT + (size_t)(h * 64 + dh * 32 + d) * NN + n0 + nc) = u.v;
  }
  // epilogue 2: s partials (pre-scaled by log2 e), atomic accumulate
  if (t < 64) {
    const int n = t & 31;
    const int which = t >> 5;      // 0 = src, 1 = dst
    const float* av = a + h * 128 + which * 64 + dh * 32;
    float s = 0.f;
#pragma unroll 8
    for (int d = 0; d < 32; ++d) s = fmaf(Td[d][n], av[d], s);
    const float LOG2E = 1.4426950408889634f;
    atomicAdd((which ? sdst : ssrc) + h * NN + n0 + n, s * LOG2E);
  }
}

// ---------------------------------------------------------------------------
// Kernel 2: barrier-free flash-GAT j-loop WITH explicit register
// double-buffering of the streamed adj/sdst. grid 512 = rowtile32(128) x
// head(4), swizzled so all 4 heads of a rowtile share an XCD. 512 thr =
// 8 waves = 8 j-chunks of 512 cols (16 iters of 32). V fragments read
// directly from L2-resident WxT. Merge at end only (3 barriers).
// ---------------------------------------------------------------------------
__global__ __launch_bounds__(512, 4) void gat_k2(
    const int* __restrict__ adj, const short* __restrict__ WxT,
    const float* __restrict__ ssrc, const float* __restrict__ sdst,
    const float* __restrict__ bias, float* __restrict__ out)
{
  __shared__ float MRG[4][32][68];
  __shared__ float Lm[8][32];

  const int b  = blockIdx.x;
  // b = rtHi*32 + h*8 + rtLo : all 4 heads of a rowtile land on same XCD (%8)
  const int rt = (b & 7) | ((b >> 5) << 3);   // 0..127
  const int h  = (b >> 3) & 3;
  const int t  = threadIdx.x;
  const int w  = t >> 6, lane = t & 63;
  const int lm = lane & 15, q = lane >> 4;
  const int jc = w;                 // j-chunk 0..7 (512 cols each)
  const int jbase = jc * 512;
  const int ib = rt * 32;
  const int i0 = ib + lm, i1 = i0 + 16;

  const float src0 = ssrc[h * NN + i0] - 1000.0f;
  const float src1 = ssrc[h * NN + i1] - 1000.0f;

  const short one = 0x3F80;
  s16x8 bones = {};
  if (lm == 0) {
    bones[0]=one; bones[1]=one; bones[2]=one; bones[3]=one;
    bones[4]=one; bones[5]=one; bones[6]=one; bones[7]=one;
  }

  f32x4 acc[2][4] = {};
  f32x4 accl[2] = {};

  // per-lane stream base pointers (already offset by jbase + q*8)
  const short* Vl    = WxT + (size_t)(h * 64 + lm) * NN + jbase + q * 8;
  const int*   arow0 = adj + (size_t)i0 * NN + jbase + q * 8;
  const int*   arow1 = adj + (size_t)i1 * NN + jbase + q * 8;
  const float* srow  = sdst + h * NN + jbase + q * 8;

  // explicit double buffer for the streamed operands
  int4   Ab[2][4];
  float4 Sb[2][2];
  Ab[0][0] = ((const int4*)arow0)[0]; Ab[0][1] = ((const int4*)(arow0 + 4))[0];
  Ab[0][2] = ((const int4*)arow1)[0]; Ab[0][3] = ((const int4*)(arow1 + 4))[0];
  Sb[0][0] = ((const float4*)srow)[0]; Sb[0][1] = ((const float4*)(srow + 4))[0];

#pragma unroll 2
  for (int js = 0; js < 16; ++js) {
    const int cur = js & 1, nxt = cur ^ 1;
    const int j = js * 32;

    // V fragments for this step (L2 hits; consumed ~200cy later at MFMA)
    s16x8 bf[4];
#pragma unroll
    for (int c = 0; c < 4; ++c)
      bf[c] = *(const s16x8*)(Vl + (size_t)c * 16 * NN + j);

    // prefetch NEXT step's adj/sdst into the other buffer half
    const int jn = (js < 15 ? j + 32 : j);
    Ab[nxt][0] = ((const int4*)(arow0 + jn))[0];
    Ab[nxt][1] = ((const int4*)(arow0 + jn + 4))[0];
    Ab[nxt][2] = ((const int4*)(arow1 + jn))[0];
    Ab[nxt][3] = ((const int4*)(arow1 + jn + 4))[0];
    Sb[nxt][0] = ((const float4*)(srow + jn))[0];
    Sb[nxt][1] = ((const float4*)(srow + jn + 4))[0];

    const float4 S0 = Sb[cur][0], S1 = Sb[cur][1];
#pragma unroll
    for (int rf = 0; rf < 2; ++rf) {
      const float src_i = rf ? src1 : src0;
      const int4 Aa = Ab[cur][rf * 2];
      const int4 Ac = Ab[cur][rf * 2 + 1];
      float p[8];
#define PGEN(dv, av, idx)                                                     \
      { float tp = src_i + (dv);                                              \
        float u  = fmaxf(tp, fmaf(tp, 0.2f, -800.0f));                        \
        u = fmaf((float)(av), 1000.0f, u);                                    \
        p[idx] = hexp2(u); }
      PGEN(S0.x, Aa.x, 0) PGEN(S0.y, Aa.y, 1)
      PGEN(S0.z, Aa.z, 2) PGEN(S0.w, Aa.w, 3)
      PGEN(S1.x, Ac.x, 4) PGEN(S1.y, Ac.y, 5)
      PGEN(S1.z, Ac.z, 6) PGEN(S1.w, Ac.w, 7)
#undef PGEN
      union { int i4[4]; s16x8 v; } af;
      af.i4[0] = pkbf(p[0], p[1]);
      af.i4[1] = pkbf(p[2], p[3]);
      af.i4[2] = pkbf(p[4], p[5]);
      af.i4[3] = pkbf(p[6], p[7]);
#pragma unroll
      for (int c = 0; c < 4; ++c)
        acc[rf][c] = __builtin_amdgcn_mfma_f32_16x16x32_bf16(af.v, bf[c], acc[rf][c], 0, 0, 0);
      accl[rf] = __builtin_amdgcn_mfma_f32_16x16x32_bf16(af.v, bones, accl[rf], 0, 0, 0);
    }
  }

  // ---- merge 8 j-chunks: tree in LDS (end-of-kernel only) ----
  if (lm == 0) {
#pragma unroll
    for (int rf = 0; rf < 2; ++rf)
#pragma unroll
      for (int g = 0; g < 4; ++g)
        Lm[w][rf * 16 + q * 4 + g] = accl[rf][g];
  }
  if (w >= 4) {
#pragma unroll
    for (int rf = 0; rf < 2; ++rf)
#pragma unroll
      for (int c = 0; c < 4; ++c)
#pragma unroll
        for (int g = 0; g < 4; ++g)
          MRG[w - 4][rf * 16 + q * 4 + g][c * 16 + lm] = acc[rf][c][g];
  }
  __syncthreads();
  if (w < 4) {
#pragma unroll
    for (int rf = 0; rf < 2; ++rf)
#pragma unroll
      for (int c = 0; c < 4; ++c)
#pragma unroll
        for (int g = 0; g < 4; ++g)
          acc[rf][c][g] += MRG[w][rf * 16 + q * 4 + g][c * 16 + lm];
  }
  __syncthreads();
  if (w >= 1 && w < 4) {
#pragma unroll
    for (int rf = 0; rf < 2; ++rf)
#pragma unroll
      for (int c = 0; c < 4; ++c)
#pragma unroll
        for (int g = 0; g < 4; ++g)
          MRG[w - 1][rf * 16 + q * 4 + g][c * 16 + lm] = acc[rf][c][g];
  }
  __syncthreads();
  if (w == 0) {
#pragma unroll
    for (int rf = 0; rf < 2; ++rf) {
#pragma unroll
      for (int g = 0; g < 4; ++g) {
        const int row = rf * 16 + q * 4 + g;
        float l = 0.f;
#pragma unroll
        for (int ww = 0; ww < 8; ++ww) l += Lm[ww][row];
        const float inv = 1.0f / l;
        const int grow = ib + row;
#pragma unroll
        for (int c = 0; c < 4; ++c) {
          const int col = c * 16 + lm;
          float v = acc[rf][c][g]
                  + MRG[0][row][col] + MRG[1][row][col] + MRG[2][row][col];
          float o = fmaf(v, inv, bias[h * 64 + col]);
          out[(size_t)grow * 256 + h * 64 + col] = fmaxf(o, 0.0f);
        }
      }
    }
  }
}

// ---------------------------------------------------------------------------
extern "C" void kernel_launch(void* const* d_in, const int* in_sizes, int n_in,
                              void* d_out, int out_size, void* d_ws, size_t ws_size,
                              hipStream_t stream) {
  const float* x    = (const float*)d_in[0];
  const int*   adj  = (const int*)d_in[1];
  const float* W    = (const float*)d_in[2];
  const float* a    = (const float*)d_in[3];
  const float* bias = (const float*)d_in[4];
  float* out = (float*)d_out;

  short* WxT  = (short*)d_ws;                                  // 2 MB bf16
  float* ssrc = (float*)((char*)d_ws + (size_t)NH * DD * NN * 2);
  float* sdst = ssrc + NH * NN;

  hipMemsetAsync(ssrc, 0, (size_t)2 * NH * NN * sizeof(float), stream);
  gat_k1<<<1024, 256, 0, stream>>>(x, W, a, WxT, ssrc, sdst);
  gat_k2<<<512, 512, 0, stream>>>(adj, WxT, ssrc, sdst, bias, out);
}

// Round 7
// 148.395 us; speedup vs baseline: 1.2264x; 1.1942x over previous
//
#include <hip/hip_runtime.h>
#include <hip/hip_bf16.h>

#define NN   4096
#define FIN  512
#define NH   4
#define DD   64

typedef float f32x4 __attribute__((ext_vector_type(4)));
typedef short s16x8 __attribute__((ext_vector_type(8)));

// manual RNE float->bf16
__device__ __forceinline__ short bfbits(float f) {
  union { float f; unsigned u; } v; v.f = f;
  unsigned r = v.u + 0x7FFFu + ((v.u >> 16) & 1u);
  return (short)(r >> 16);
}

// packed pair float->bf16
__device__ __forceinline__ int pkbf(float a, float b) {
  union { float f; unsigned u; } va, vb;
  va.f = a; vb.f = b;
  unsigned ra = (va.u + 0x7FFFu + ((va.u >> 16) & 1u)) >> 16;
  unsigned rb = (vb.u + 0x7FFFu + ((vb.u >> 16) & 1u)) & 0xFFFF0000u;
  return (int)(ra | rb);
}

__device__ __forceinline__ float hexp2(float x) {
#if __has_builtin(__builtin_amdgcn_exp2f)
  return __builtin_amdgcn_exp2f(x);
#else
  return __builtin_exp2f(x);
#endif
}

// ---------------------------------------------------------------------------
// Kernel 0: bit-pack adj (0/1 int32) -> 1 bit. Row-major: u32 word w of row i
// covers cols w*32..+31, bit j%32. Via wave ballot: iter `it` packs cols
// it*64..+63 into one u64. 1 row per wave; fully coalesced both sides.
// ---------------------------------------------------------------------------
__global__ __launch_bounds__(256) void gat_pack(
    const int* __restrict__ adj, unsigned long long* __restrict__ bits)
{
  const int row  = (blockIdx.x << 2) | (threadIdx.x >> 6);
  const int lane = threadIdx.x & 63;
  const int* arow = adj + (size_t)row * NN;
  unsigned long long mine = 0;
#pragma unroll 8
  for (int it = 0; it < 64; ++it) {
    int v = arow[it * 64 + lane];
    unsigned long long b = __ballot(v != 0);
    if (lane == it) mine = b;
  }
  bits[(size_t)row * 64 + lane] = mine;
}

// ---------------------------------------------------------------------------
// Kernel 1: Wx = X @ W[h], split-K, no in-loop barriers (r5 structure, passed).
// grid 1024 = rowtile32(128) x head(4) x dhalf(2); 4 waves own K-quarters.
// NEW: epilogue writes V2 in TILED layout V2[h][jt][d][32] (jt = n/32) so k2's
// B-fragment loads are 1KB-contiguous. Plus atomicAdd s_src/s_dst partials.
// ---------------------------------------------------------------------------
__global__ __launch_bounds__(256, 4) void gat_k1(
    const float* __restrict__ x, const float* __restrict__ W,
    const float* __restrict__ a,
    short* __restrict__ V2, float* __restrict__ ssrc, float* __restrict__ sdst)
{
  __shared__ float Ms[3][32][34];   // K-split merge
  __shared__ float Td[32][33];      // [d][n] transposed tile for epilogue

  const int b  = blockIdx.x;
  const int rt = b >> 3;            // 0..127
  const int h  = (b >> 1) & 3;
  const int dh = b & 1;
  const int n0 = rt * 32;
  const int t  = threadIdx.x;
  const int w  = t >> 6, lane = t & 63;
  const int lm = lane & 15, q = lane >> 4;

  const float* Wh = W + (size_t)h * (FIN * DD) + dh * 32;
  f32x4 acc[2][2] = {};

#pragma unroll
  for (int ks = 0; ks < 4; ++ks) {
    const int k0 = w * 128 + ks * 32 + q * 8;
    s16x8 af[2];
#pragma unroll
    for (int rf = 0; rf < 2; ++rf) {
      const float* xp = x + (size_t)(n0 + rf * 16 + lm) * FIN + k0;
      float4 a0 = ((const float4*)xp)[0];
      float4 a1 = ((const float4*)xp)[1];
      union { short s[8]; s16x8 v; } u;
      u.s[0]=bfbits(a0.x); u.s[1]=bfbits(a0.y); u.s[2]=bfbits(a0.z); u.s[3]=bfbits(a0.w);
      u.s[4]=bfbits(a1.x); u.s[5]=bfbits(a1.y); u.s[6]=bfbits(a1.z); u.s[7]=bfbits(a1.w);
      af[rf] = u.v;
    }
    s16x8 bfr[2];
#pragma unroll
    for (int c = 0; c < 2; ++c) {
      const float* wp = Wh + (size_t)k0 * DD + c * 16 + lm;
      union { short s[8]; s16x8 v; } u;
#pragma unroll
      for (int e = 0; e < 8; ++e) u.s[e] = bfbits(wp[e * DD]);
      bfr[c] = u.v;
    }
#pragma unroll
    for (int rf = 0; rf < 2; ++rf)
#pragma unroll
      for (int c = 0; c < 2; ++c)
        acc[rf][c] = __builtin_amdgcn_mfma_f32_16x16x32_bf16(af[rf], bfr[c], acc[rf][c], 0, 0, 0);
  }

  if (w != 0) {
#pragma unroll
    for (int rf = 0; rf < 2; ++rf)
#pragma unroll
      for (int c = 0; c < 2; ++c)
#pragma unroll
        for (int g = 0; g < 4; ++g)
          Ms[w - 1][rf * 16 + q * 4 + g][c * 16 + lm] = acc[rf][c][g];
  }
  __syncthreads();
  if (w == 0) {
#pragma unroll
    for (int rf = 0; rf < 2; ++rf)
#pragma unroll
      for (int c = 0; c < 2; ++c)
#pragma unroll
        for (int g = 0; g < 4; ++g) {
          const int row = rf * 16 + q * 4 + g, col = c * 16 + lm;
          float v = acc[rf][c][g] + Ms[0][row][col] + Ms[1][row][col] + Ms[2][row][col];
          Td[col][row] = v;   // [d][n]
        }
  }
  __syncthreads();

  // epilogue 1: V2[h][rt][dh*32+d][0..31] bf16, tiled
  {
    const int d = t >> 3, nc = (t & 7) * 4;
    union { short s[4]; int2 v; } u;
#pragma unroll
    for (int e = 0; e < 4; ++e) u.s[e] = bfbits(Td[d][nc + e]);
    *(int2*)(V2 + ((size_t)(h * 128 + rt) * 64 + dh * 32 + d) * 32 + nc) = u.v;
  }
  // epilogue 2: s partials (pre-scaled by log2 e)
  if (t < 64) {
    const int n = t & 31;
    const int which = t >> 5;
    const float* av = a + h * 128 + which * 64 + dh * 32;
    float s = 0.f;
#pragma unroll 8
    for (int d = 0; d < 32; ++d) s = fmaf(Td[d][n], av[d], s);
    const float LOG2E = 1.4426950408889634f;
    atomicAdd((which ? sdst : ssrc) + h * NN + n0 + n, s * LOG2E);
  }
}

// ---------------------------------------------------------------------------
// Kernel 2: barrier-free flash-GAT. grid 512 = rowtile32(128) x head(4);
// 512 thr = 8 waves = 8 j-chunks of 512. Per wave: 16 iters of 32 cols.
// V fragments: 1KB-contiguous loads from tiled V2 (L2-resident).
// adj: 1 u32 mask word per row per iter (uint4 per 4-iter superstep,
// prefetched one superstep ahead). End: LDS tree merge (3 barriers).
// ---------------------------------------------------------------------------
__global__ __launch_bounds__(512, 4) void gat_k2(
    const unsigned* __restrict__ bits, const short* __restrict__ V2,
    const float* __restrict__ ssrc, const float* __restrict__ sdst,
    const float* __restrict__ bias, float* __restrict__ out)
{
  __shared__ float MRG[4][32][68];
  __shared__ float Lm[8][32];

  const int b  = blockIdx.x;
  const int rt = b >> 2;            // 0..127
  const int h  = b & 3;
  const int t  = threadIdx.x;
  const int w  = t >> 6, lane = t & 63;
  const int lm = lane & 15, q = lane >> 4;
  const int jc = w;                 // j-chunk (512 cols)
  const int ib = rt * 32;
  const int i0 = ib + lm, i1 = i0 + 16;

  const float src0 = ssrc[h * NN + i0] - 1000.0f;
  const float src1 = ssrc[h * NN + i1] - 1000.0f;

  const short one = 0x3F80;
  s16x8 bones = {};
  if (lm == 0) {
    bones[0]=one; bones[1]=one; bones[2]=one; bones[3]=one;
    bones[4]=one; bones[5]=one; bones[6]=one; bones[7]=one;
  }

  f32x4 acc[2][4] = {};
  f32x4 accl[2] = {};

  const short*  Vb  = V2 + (size_t)h * 262144 + (size_t)jc * 16 * 2048
                      + lm * 32 + q * 8;                 // +c*512, +js*2048
  const float*  sdh = sdst + h * NN + jc * 512 + q * 8;  // +js*32
  const unsigned* b0 = bits + (size_t)i0 * 128 + jc * 16;
  const unsigned* b1 = bits + (size_t)i1 * 128 + jc * 16;

  unsigned Wd0[4], Wd1[4], nWd0[4], nWd1[4];
  *(uint4*)Wd0 = ((const uint4*)b0)[0];
  *(uint4*)Wd1 = ((const uint4*)b1)[0];

  const int shq = q * 8;

  for (int s = 0; s < 4; ++s) {
    if (s < 3) {
      *(uint4*)nWd0 = ((const uint4*)b0)[s + 1];
      *(uint4*)nWd1 = ((const uint4*)b1)[s + 1];
    }
#pragma unroll
    for (int jsub = 0; jsub < 4; ++jsub) {
      const int js = s * 4 + jsub;

      s16x8 bf[4];
#pragma unroll
      for (int c = 0; c < 4; ++c)
        bf[c] = *(const s16x8*)(Vb + js * 2048 + c * 512);

      const float* sb = sdh + js * 32;
      const float4 S0 = ((const float4*)sb)[0];
      const float4 S1 = ((const float4*)sb)[1];

      const unsigned wq0 = Wd0[jsub] >> shq;
      const unsigned wq1 = Wd1[jsub] >> shq;

#pragma unroll
      for (int rf = 0; rf < 2; ++rf) {
        const float src_i = rf ? src1 : src0;
        const unsigned wq = rf ? wq1 : wq0;
        float p[8];
#define PGEN(dv, e)                                                           \
        { float tp = src_i + (dv);                                            \
          float u  = fmaxf(tp, fmaf(tp, 0.2f, -800.0f));                      \
          u = fmaf((float)((wq >> (e)) & 1u), 1000.0f, u);                    \
          p[e] = hexp2(u); }
        PGEN(S0.x, 0) PGEN(S0.y, 1) PGEN(S0.z, 2) PGEN(S0.w, 3)
        PGEN(S1.x, 4) PGEN(S1.y, 5) PGEN(S1.z, 6) PGEN(S1.w, 7)
#undef PGEN
        union { int i4[4]; s16x8 v; } af;
        af.i4[0] = pkbf(p[0], p[1]);
        af.i4[1] = pkbf(p[2], p[3]);
        af.i4[2] = pkbf(p[4], p[5]);
        af.i4[3] = pkbf(p[6], p[7]);
#pragma unroll
        for (int c = 0; c < 4; ++c)
          acc[rf][c] = __builtin_amdgcn_mfma_f32_16x16x32_bf16(af.v, bf[c], acc[rf][c], 0, 0, 0);
        accl[rf] = __builtin_amdgcn_mfma_f32_16x16x32_bf16(af.v, bones, accl[rf], 0, 0, 0);
      }
    }
#pragma unroll
    for (int e = 0; e < 4; ++e) { Wd0[e] = nWd0[e]; Wd1[e] = nWd1[e]; }
  }

  // ---- merge 8 j-chunks (end-of-kernel tree) ----
  if (lm == 0) {
#pragma unroll
    for (int rf = 0; rf < 2; ++rf)
#pragma unroll
      for (int g = 0; g < 4; ++g)
        Lm[w][rf * 16 + q * 4 + g] = accl[rf][g];
  }
  if (w >= 4) {
#pragma unroll
    for (int rf = 0; rf < 2; ++rf)
#pragma unroll
      for (int c = 0; c < 4; ++c)
#pragma unroll
        for (int g = 0; g < 4; ++g)
          MRG[w - 4][rf * 16 + q * 4 + g][c * 16 + lm] = acc[rf][c][g];
  }
  __syncthreads();
  if (w < 4) {
#pragma unroll
    for (int rf = 0; rf < 2; ++rf)
#pragma unroll
      for (int c = 0; c < 4; ++c)
#pragma unroll
        for (int g = 0; g < 4; ++g)
          acc[rf][c][g] += MRG[w][rf * 16 + q * 4 + g][c * 16 + lm];
  }
  __syncthreads();
  if (w >= 1 && w < 4) {
#pragma unroll
    for (int rf = 0; rf < 2; ++rf)
#pragma unroll
      for (int c = 0; c < 4; ++c)
#pragma unroll
        for (int g = 0; g < 4; ++g)
          MRG[w - 1][rf * 16 + q * 4 + g][c * 16 + lm] = acc[rf][c][g];
  }
  __syncthreads();
  if (w == 0) {
#pragma unroll
    for (int rf = 0; rf < 2; ++rf) {
#pragma unroll
      for (int g = 0; g < 4; ++g) {
        const int row = rf * 16 + q * 4 + g;
        float l = 0.f;
#pragma unroll
        for (int ww = 0; ww < 8; ++ww) l += Lm[ww][row];
        const float inv = 1.0f / l;
        const int grow = ib + row;
#pragma unroll
        for (int c = 0; c < 4; ++c) {
          const int col = c * 16 + lm;
          float v = acc[rf][c][g]
                  + MRG[0][row][col] + MRG[1][row][col] + MRG[2][row][col];
          float o = fmaf(v, inv, bias[h * 64 + col]);
          out[(size_t)grow * 256 + h * 64 + col] = fmaxf(o, 0.0f);
        }
      }
    }
  }
}

// ---------------------------------------------------------------------------
extern "C" void kernel_launch(void* const* d_in, const int* in_sizes, int n_in,
                              void* d_out, int out_size, void* d_ws, size_t ws_size,
                              hipStream_t stream) {
  const float* x    = (const float*)d_in[0];
  const int*   adj  = (const int*)d_in[1];
  const float* W    = (const float*)d_in[2];
  const float* a    = (const float*)d_in[3];
  const float* bias = (const float*)d_in[4];
  float* out = (float*)d_out;

  // workspace: V2 (2MB) | ssrc (64KB) | sdst (64KB) | bits (2MB)
  short* V2   = (short*)d_ws;
  float* ssrc = (float*)((char*)d_ws + (size_t)2 * 1024 * 1024);
  float* sdst = ssrc + NH * NN;
  unsigned long long* bits =
      (unsigned long long*)((char*)d_ws + (size_t)2 * 1024 * 1024 + 128 * 1024);

  hipMemsetAsync(ssrc, 0, (size_t)2 * NH * NN * sizeof(float), stream);
  gat_pack<<<1024, 256, 0, stream>>>(adj, bits);
  gat_k1<<<1024, 256, 0, stream>>>(x, W, a, V2, ssrc, sdst);
  gat_k2<<<512, 512, 0, stream>>>((const unsigned*)bits, V2, ssrc, sdst, bias, out);
}

// Round 8
// 137.893 us; speedup vs baseline: 1.3198x; 1.0762x over previous
//
#include <hip/hip_runtime.h>
#include <hip/hip_bf16.h>

#define NN   4096
#define FIN  512
#define NH   4
#define DD   64

typedef float f32x4 __attribute__((ext_vector_type(4)));
typedef short s16x8 __attribute__((ext_vector_type(8)));

// manual RNE float->bf16
__device__ __forceinline__ short bfbits(float f) {
  union { float f; unsigned u; } v; v.f = f;
  unsigned r = v.u + 0x7FFFu + ((v.u >> 16) & 1u);
  return (short)(r >> 16);
}

// packed pair float->bf16
__device__ __forceinline__ int pkbf(float a, float b) {
  union { float f; unsigned u; } va, vb;
  va.f = a; vb.f = b;
  unsigned ra = (va.u + 0x7FFFu + ((va.u >> 16) & 1u)) >> 16;
  unsigned rb = (vb.u + 0x7FFFu + ((vb.u >> 16) & 1u)) & 0xFFFF0000u;
  return (int)(ra | rb);
}

__device__ __forceinline__ float hexp2(float x) {
#if __has_builtin(__builtin_amdgcn_exp2f)
  return __builtin_amdgcn_exp2f(x);
#else
  return __builtin_exp2f(x);
#endif
}

// ---------------------------------------------------------------------------
// Fused pre-kernel: grid 768 = 512 pack-blocks + 256 k1-blocks, interleaved
// 2:1 so HBM-bound pack co-resides with compute-bound k1 on every CU.
//  pack: adj (0/1 int32) -> 1-bit mask via wave ballot, 8 rows/block.
//  k1:   Wx = X @ W[h] (LDS-staged coalesced bf16 MFMA, 64-row tile,
//        K-chunks of 128), writes V2 tiled [h][rt32][d][32] + s_src/s_dst
//        (scaled by log2 e) directly (no atomics).
// ---------------------------------------------------------------------------
__global__ __launch_bounds__(512, 4) void gat_pre(
    const int* __restrict__ adj, const float* __restrict__ x,
    const float* __restrict__ W, const float* __restrict__ a,
    unsigned long long* __restrict__ bits, short* __restrict__ V2,
    float* __restrict__ ssrc, float* __restrict__ sdst)
{
  __shared__ __align__(16) char sm[34816];
  short* As = (short*)sm;                 // [64 rows][136] (128 used)
  short* Bs = (short*)(sm + 17408);       // [64 d][136]
  float* Cs = (float*)sm;                 // overlay: [64 d][65] after MFMA

  const int b = blockIdx.x;
  const int t = threadIdx.x;
  const int w = t >> 6, lane = t & 63;

  const int g3 = b / 3, m3 = b - g3 * 3;
  if (m3 < 2) {
    // ---------------- pack ----------------
    const int row = g3 * 2 + m3 + ((w) << 9);   // wait: need 8 rows per block
    // 512 pack-blocks x 8 waves = 4096 rows: row = pb*8 + w
    const int pb = g3 * 2 + m3;
    const int rrow = (pb << 3) | w;
    const int* arow = adj + (size_t)rrow * NN;
    unsigned long long mine = 0;
#pragma unroll 8
    for (int it = 0; it < 64; ++it) {
      int v = arow[it * 64 + lane];
      unsigned long long bl = __ballot(v != 0);
      if (lane == it) mine = bl;
    }
    bits[(size_t)rrow * 64 + lane] = mine;
    (void)row;
    return;
  }

  // ---------------- k1 ----------------
  const int b2 = g3;              // 0..255
  const int h  = b2 >> 6;
  const int r  = b2 & 63;
  const int n0 = r * 64;
  const int lm = lane & 15, q = lane >> 4;
  const int rs = w & 3, cs = w >> 2;

  f32x4 acc[2] = {};
  const float* Wh = W + (size_t)h * (FIN * DD);

  for (int kq = 0; kq < 4; ++kq) {
    // stage A: x[n0+row][kq*128 + fl .. +16) -> As[row][fl]
    {
      const int row = t >> 3, fl = (t & 7) * 16;
      const float* xp = x + (size_t)(n0 + row) * FIN + kq * 128 + fl;
      float4 v0 = ((const float4*)xp)[0];
      float4 v1 = ((const float4*)xp)[1];
      float4 v2 = ((const float4*)xp)[2];
      float4 v3 = ((const float4*)xp)[3];
      union { short s[8]; int4 v; } u0, u1;
      u0.s[0]=bfbits(v0.x); u0.s[1]=bfbits(v0.y); u0.s[2]=bfbits(v0.z); u0.s[3]=bfbits(v0.w);
      u0.s[4]=bfbits(v1.x); u0.s[5]=bfbits(v1.y); u0.s[6]=bfbits(v1.z); u0.s[7]=bfbits(v1.w);
      u1.s[0]=bfbits(v2.x); u1.s[1]=bfbits(v2.y); u1.s[2]=bfbits(v2.z); u1.s[3]=bfbits(v2.w);
      u1.s[4]=bfbits(v3.x); u1.s[5]=bfbits(v3.y); u1.s[6]=bfbits(v3.z); u1.s[7]=bfbits(v3.w);
      *(int4*)(As + row * 136 + fl)     = u0.v;
      *(int4*)(As + row * 136 + fl + 8) = u1.v;
    }
    // stage B transposed: W[h][kq*128+fl][dc..dc+16) -> Bs[d][fl]
    {
      const int fl = t >> 2, dc = (t & 3) * 16;
      const float* wp = Wh + (size_t)(kq * 128 + fl) * DD + dc;
      float4 w0 = ((const float4*)wp)[0];
      float4 w1 = ((const float4*)wp)[1];
      float4 w2 = ((const float4*)wp)[2];
      float4 w3 = ((const float4*)wp)[3];
      Bs[(dc+ 0)*136+fl]=bfbits(w0.x); Bs[(dc+ 1)*136+fl]=bfbits(w0.y);
      Bs[(dc+ 2)*136+fl]=bfbits(w0.z); Bs[(dc+ 3)*136+fl]=bfbits(w0.w);
      Bs[(dc+ 4)*136+fl]=bfbits(w1.x); Bs[(dc+ 5)*136+fl]=bfbits(w1.y);
      Bs[(dc+ 6)*136+fl]=bfbits(w1.z); Bs[(dc+ 7)*136+fl]=bfbits(w1.w);
      Bs[(dc+ 8)*136+fl]=bfbits(w2.x); Bs[(dc+ 9)*136+fl]=bfbits(w2.y);
      Bs[(dc+10)*136+fl]=bfbits(w2.z); Bs[(dc+11)*136+fl]=bfbits(w2.w);
      Bs[(dc+12)*136+fl]=bfbits(w3.x); Bs[(dc+13)*136+fl]=bfbits(w3.y);
      Bs[(dc+14)*136+fl]=bfbits(w3.z); Bs[(dc+15)*136+fl]=bfbits(w3.w);
    }
    __syncthreads();
#pragma unroll
    for (int s = 0; s < 4; ++s) {
      s16x8 af = *(const s16x8*)(As + (rs * 16 + lm) * 136 + s * 32 + q * 8);
#pragma unroll
      for (int c = 0; c < 2; ++c) {
        s16x8 bf = *(const s16x8*)(Bs + (cs * 32 + c * 16 + lm) * 136 + s * 32 + q * 8);
        acc[c] = __builtin_amdgcn_mfma_f32_16x16x32_bf16(af, bf, acc[c], 0, 0, 0);
      }
    }
    __syncthreads();
  }

  // scatter C transposed into Cs[d][n]
#pragma unroll
  for (int c = 0; c < 2; ++c)
#pragma unroll
    for (int g = 0; g < 4; ++g)
      Cs[(cs * 32 + c * 16 + lm) * 65 + (rs * 16 + q * 4 + g)] = acc[c][g];
  __syncthreads();

  // epilogue 1: V2[h][r*2 + (nc>=32)][d][nc&31] bf16, tiled 16B stores
  {
    const int d = t >> 3, nc = (t & 7) * 8;
    union { short s[8]; int4 v; } u;
#pragma unroll
    for (int e = 0; e < 8; ++e) u.s[e] = bfbits(Cs[d * 65 + nc + e]);
    *(int4*)(V2 + ((size_t)(h * 128 + r * 2 + (nc >> 5)) * 64 + d) * 32 + (nc & 31)) = u.v;
  }
  // epilogue 2: s_src / s_dst (scaled by log2 e), direct store
  if (t < 128) {
    const int n = t & 63;
    const int isdst = t >> 6;
    const float* av = a + h * 128 + isdst * 64;
    float s = 0.f;
#pragma unroll 8
    for (int d = 0; d < 64; ++d) s = fmaf(Cs[d * 65 + n], av[d], s);
    const float LOG2E = 1.4426950408889634f;
    (isdst ? sdst : ssrc)[h * NN + n0 + n] = s * LOG2E;
  }
}

// ---------------------------------------------------------------------------
// Kernel 2: barrier-free flash-GAT with register double-buffered V/sdst.
// grid 512 = rowtile32(128) x head(4); 8 waves = 8 j-chunks of 512.
// V: 1KB-contiguous tiled loads, prefetched one iter ahead. Masks: uint4 per
// 4-iter superstep, prefetched one superstep ahead. End: LDS tree merge.
// ---------------------------------------------------------------------------
__global__ __launch_bounds__(512, 4) void gat_k2(
    const unsigned* __restrict__ bits, const short* __restrict__ V2,
    const float* __restrict__ ssrc, const float* __restrict__ sdst,
    const float* __restrict__ bias, float* __restrict__ out)
{
  __shared__ float MRG[4][32][68];
  __shared__ float Lm[8][32];

  const int b  = blockIdx.x;
  const int rt = b >> 2;            // 0..127
  const int h  = b & 3;
  const int t  = threadIdx.x;
  const int w  = t >> 6, lane = t & 63;
  const int lm = lane & 15, q = lane >> 4;
  const int jc = w;
  const int ib = rt * 32;
  const int i0 = ib + lm, i1 = i0 + 16;

  const float src0 = ssrc[h * NN + i0] - 1000.0f;
  const float src1 = ssrc[h * NN + i1] - 1000.0f;

  const short one = 0x3F80;
  s16x8 bones = {};
  if (lm == 0) {
    bones[0]=one; bones[1]=one; bones[2]=one; bones[3]=one;
    bones[4]=one; bones[5]=one; bones[6]=one; bones[7]=one;
  }

  f32x4 acc[2][4] = {};
  f32x4 accl[2] = {};

  const short*  Vb  = V2 + (size_t)h * 262144 + (size_t)jc * 16 * 2048
                      + lm * 32 + q * 8;                 // +js*2048 +c*512
  const float*  sdh = sdst + h * NN + jc * 512 + q * 8;  // +js*32
  const unsigned* b0 = bits + (size_t)i0 * 128 + jc * 16;
  const unsigned* b1 = bits + (size_t)i1 * 128 + jc * 16;

  unsigned Wd0[4], Wd1[4], nWd0[4], nWd1[4];
  *(uint4*)Wd0 = ((const uint4*)b0)[0];
  *(uint4*)Wd1 = ((const uint4*)b1)[0];

  // register double buffer: V frags + sdst one iteration ahead
  s16x8 bfc[4];
#pragma unroll
  for (int c = 0; c < 4; ++c) bfc[c] = *(const s16x8*)(Vb + c * 512);
  float4 S0 = ((const float4*)sdh)[0];
  float4 S1 = ((const float4*)(sdh + 4))[0];

  const int shq = q * 8;

  for (int s = 0; s < 4; ++s) {
    if (s < 3) {
      *(uint4*)nWd0 = ((const uint4*)b0)[s + 1];
      *(uint4*)nWd1 = ((const uint4*)b1)[s + 1];
    }
#pragma unroll
    for (int jsub = 0; jsub < 4; ++jsub) {
      const int js = s * 4 + jsub;
      const int jn = (js < 15) ? js + 1 : js;

      // prefetch next iteration's V frags + sdst
      s16x8 bfn[4];
#pragma unroll
      for (int c = 0; c < 4; ++c)
        bfn[c] = *(const s16x8*)(Vb + jn * 2048 + c * 512);
      float4 T0 = ((const float4*)(sdh + jn * 32))[0];
      float4 T1 = ((const float4*)(sdh + jn * 32 + 4))[0];

      const unsigned wq0 = Wd0[jsub] >> shq;
      const unsigned wq1 = Wd1[jsub] >> shq;

#pragma unroll
      for (int rf = 0; rf < 2; ++rf) {
        const float src_i = rf ? src1 : src0;
        const unsigned wq = rf ? wq1 : wq0;
        float p[8];
#define PGEN(dv, e)                                                           \
        { float tp = src_i + (dv);                                            \
          float u  = fmaxf(tp, fmaf(tp, 0.2f, -800.0f));                      \
          u = fmaf((float)((wq >> (e)) & 1u), 1000.0f, u);                    \
          p[e] = hexp2(u); }
        PGEN(S0.x, 0) PGEN(S0.y, 1) PGEN(S0.z, 2) PGEN(S0.w, 3)
        PGEN(S1.x, 4) PGEN(S1.y, 5) PGEN(S1.z, 6) PGEN(S1.w, 7)
#undef PGEN
        union { int i4[4]; s16x8 v; } af;
        af.i4[0] = pkbf(p[0], p[1]);
        af.i4[1] = pkbf(p[2], p[3]);
        af.i4[2] = pkbf(p[4], p[5]);
        af.i4[3] = pkbf(p[6], p[7]);
#pragma unroll
        for (int c = 0; c < 4; ++c)
          acc[rf][c] = __builtin_amdgcn_mfma_f32_16x16x32_bf16(af.v, bfc[c], acc[rf][c], 0, 0, 0);
        accl[rf] = __builtin_amdgcn_mfma_f32_16x16x32_bf16(af.v, bones, accl[rf], 0, 0, 0);
      }
#pragma unroll
      for (int c = 0; c < 4; ++c) bfc[c] = bfn[c];
      S0 = T0; S1 = T1;
    }
#pragma unroll
    for (int e = 0; e < 4; ++e) { Wd0[e] = nWd0[e]; Wd1[e] = nWd1[e]; }
  }

  // ---- merge 8 j-chunks (end-of-kernel tree) ----
  if (lm == 0) {
#pragma unroll
    for (int rf = 0; rf < 2; ++rf)
#pragma unroll
      for (int g = 0; g < 4; ++g)
        Lm[w][rf * 16 + q * 4 + g] = accl[rf][g];
  }
  if (w >= 4) {
#pragma unroll
    for (int rf = 0; rf < 2; ++rf)
#pragma unroll
      for (int c = 0; c < 4; ++c)
#pragma unroll
        for (int g = 0; g < 4; ++g)
          MRG[w - 4][rf * 16 + q * 4 + g][c * 16 + lm] = acc[rf][c][g];
  }
  __syncthreads();
  if (w < 4) {
#pragma unroll
    for (int rf = 0; rf < 2; ++rf)
#pragma unroll
      for (int c = 0; c < 4; ++c)
#pragma unroll
        for (int g = 0; g < 4; ++g)
          acc[rf][c][g] += MRG[w][rf * 16 + q * 4 + g][c * 16 + lm];
  }
  __syncthreads();
  if (w >= 1 && w < 4) {
#pragma unroll
    for (int rf = 0; rf < 2; ++rf)
#pragma unroll
      for (int c = 0; c < 4; ++c)
#pragma unroll
        for (int g = 0; g < 4; ++g)
          MRG[w - 1][rf * 16 + q * 4 + g][c * 16 + lm] = acc[rf][c][g];
  }
  __syncthreads();
  if (w == 0) {
#pragma unroll
    for (int rf = 0; rf < 2; ++rf) {
#pragma unroll
      for (int g = 0; g < 4; ++g) {
        const int row = rf * 16 + q * 4 + g;
        float l = 0.f;
#pragma unroll
        for (int ww = 0; ww < 8; ++ww) l += Lm[ww][row];
        const float inv = 1.0f / l;
        const int grow = ib + row;
#pragma unroll
        for (int c = 0; c < 4; ++c) {
          const int col = c * 16 + lm;
          float v = acc[rf][c][g]
                  + MRG[0][row][col] + MRG[1][row][col] + MRG[2][row][col];
          float o = fmaf(v, inv, bias[h * 64 + col]);
          out[(size_t)grow * 256 + h * 64 + col] = fmaxf(o, 0.0f);
        }
      }
    }
  }
}

// ---------------------------------------------------------------------------
extern "C" void kernel_launch(void* const* d_in, const int* in_sizes, int n_in,
                              void* d_out, int out_size, void* d_ws, size_t ws_size,
                              hipStream_t stream) {
  const float* x    = (const float*)d_in[0];
  const int*   adj  = (const int*)d_in[1];
  const float* W    = (const float*)d_in[2];
  const float* a    = (const float*)d_in[3];
  const float* bias = (const float*)d_in[4];
  float* out = (float*)d_out;

  // workspace: V2 (2MB) | bits (2MB) | ssrc (64KB) | sdst (64KB)
  short* V2 = (short*)d_ws;
  unsigned long long* bits =
      (unsigned long long*)((char*)d_ws + (size_t)2 * 1024 * 1024);
  float* ssrc = (float*)((char*)d_ws + (size_t)4 * 1024 * 1024);
  float* sdst = ssrc + NH * NN;

  gat_pre<<<768, 512, 0, stream>>>(adj, x, W, a, bits, V2, ssrc, sdst);
  gat_k2<<<512, 512, 0, stream>>>((const unsigned*)bits, V2, ssrc, sdst, bias, out);
}